// Round 12
// baseline (21.181 us; speedup 1.0000x reference)
//
#include <hip/hip_runtime.h>

namespace {
constexpr int B = 8, T = 12, N = 325, C = 32, K = 100;
constexpr int NPB = 5;                 // nodes (waves) per block; 325 = 5*65
constexpr int NPAIRS = N / NPB;        // 65
constexpr float EPSF = 1e-5f;
constexpr float MIN_NORM = 1e-15f;
}

typedef __attribute__((ext_vector_type(8))) short bf16x8;
typedef __attribute__((ext_vector_type(4))) float f32x4;

__device__ __forceinline__ unsigned short bf16_rne(float x) {
  unsigned int u = __float_as_uint(x);
  unsigned int r = u + 0x7FFFu + ((u >> 16) & 1u);
  return (unsigned short)(r >> 16);
}
__device__ __forceinline__ float bf16_f(unsigned short h) {
  return __uint_as_float(((unsigned int)h) << 16);
}

// One k-half: K0 = starting centroid, NKT = # of 16-wide k-tiles.
// block = 320 thr = 5 waves = 5 nodes. grid = B*NPAIRS = 520.
template<int K0, int NKT>
__global__ __launch_bounds__(320, 4) void hcd_half(
    const float* __restrict__ x_g,       // [B,T,N,C]
    const float* __restrict__ cw,        // [K,C]
    const float* __restrict__ cptr,      // [1]
    float* __restrict__ out0,            // [B,N,K]
    float* __restrict__ out1)            // [B,T,N,K]
{
  __shared__ unsigned short yh[16 * NKT][C];
  __shared__ unsigned short ylo[16 * NKT][C];
  __shared__ float y2l[16 * NKT];
  __shared__ float x2l[NPB][T];

  const int tid = threadIdx.x;
  const int b   = blockIdx.x / NPAIRS;
  const int np  = blockIdx.x % NPAIRS;
  const int n0  = np * NPB;

  const float c  = cptr[0];
  const float sc = sqrtf(c);
  const float HLN2 = 0.34657359028f;            // ln2/2
  const float KQ = (4.f / c) * HLN2 * HLN2;     // folds (2/sc)^2 * (ln2/2)^2
  const float TLOG2E = 2.88539008178f;          // 2*log2(e)

  // ---- wave 0: expmap0 of this half's centroids -> bf16 hi/lo LDS ----
  if (tid < 16 * NKT) {
    const int kg = K0 + tid;
    float y[C];
    float y2 = 0.f;
    if (kg < K) {
      float u2 = 0.f;
      #pragma unroll
      for (int q = 0; q < C / 4; ++q) {
        float4 v = *(const float4*)(cw + kg * C + 4 * q);
        y[4*q+0] = v.x; y[4*q+1] = v.y; y[4*q+2] = v.z; y[4*q+3] = v.w;
      }
      #pragma unroll
      for (int i = 0; i < C; ++i) u2 = fmaf(y[i], y[i], u2);
      float z = sc * fmaxf(sqrtf(u2), MIN_NORM);
      float E  = exp2f(z * TLOG2E);                       // e^(2z)
      float th = (E - 1.f) * __builtin_amdgcn_rcpf(E + 1.f);
      float f  = th * __builtin_amdgcn_rcpf(z);
      #pragma unroll
      for (int i = 0; i < C; ++i) y[i] *= f;
      y2 = f * f * u2;
    } else {
      #pragma unroll
      for (int i = 0; i < C; ++i) y[i] = 0.f;
    }
    #pragma unroll
    for (int i = 0; i < C; ++i) {
      unsigned short hi = bf16_rne(y[i]);
      yh[tid][i]  = hi;
      ylo[tid][i] = bf16_rne(y[i] - bf16_f(hi));
    }
    y2l[tid] = y2;
  }

  // ---- wave 1: x squared norms (fp32 exact) for the 5 nodes ----
  if (tid >= 64 && tid < 64 + NPB * T) {
    int i  = tid - 64;
    int nl = i / T, t = i - nl * T;
    const float* xr = x_g + ((size_t)(b * T + t) * N + (n0 + nl)) * C;
    float s = 0.f;
    #pragma unroll
    for (int q = 0; q < C / 4; ++q) {
      float4 v = *(const float4*)(xr + 4 * q);
      s = fmaf(v.x, v.x, s); s = fmaf(v.y, v.y, s);
      s = fmaf(v.z, v.z, s); s = fmaf(v.w, v.w, s);
    }
    x2l[nl][t] = s;
  }

  // ---- A-fragment: wave's node, 16 t-rows (12 real + 4 zero) ----
  const int w    = tid >> 6;            // 0..4 -> node
  const int lane = tid & 63;
  const int l16  = lane & 15;           // A row (t) / B col (k) / D col (k)
  const int g    = lane >> 4;           // 8-elem chunk of C
  const int n    = n0 + w;

  const int trow = (l16 < T) ? l16 : 0;
  const float* xrow = x_g + (((size_t)(b * T + trow) * N + n) * C) + 8 * g;
  float4 v0 = *(const float4*)(xrow);
  float4 v1 = *(const float4*)(xrow + 4);
  if (l16 >= T) { v0 = make_float4(0,0,0,0); v1 = make_float4(0,0,0,0); }
  float xe[8] = {v0.x, v0.y, v0.z, v0.w, v1.x, v1.y, v1.z, v1.w};
  bf16x8 ah, al;
  #pragma unroll
  for (int i = 0; i < 8; ++i) {
    unsigned short hi = bf16_rne(xe[i]);
    ah[i] = (short)hi;
    al[i] = (short)bf16_rne(xe[i] - bf16_f(hi));
  }
  __syncthreads();

  // ---- kt-invariant per-reg terms ----
  const float c2 = c * c;
  const float tc = 2.f * c;
  float x2r[4], Bcr[4], Bc2r[4], c2x2r[4];
  #pragma unroll
  for (int reg = 0; reg < 4; ++reg) {
    int t = 4 * g + reg;
    float x2 = x2l[w][(t < T) ? t : 0];
    x2r[reg]   = x2;
    Bcr[reg]   = fmaf(-c, x2, 1.f);     // 1 - c*x2
    Bc2r[reg]  = Bcr[reg] * Bcr[reg];
    c2x2r[reg] = c2 * x2;
  }

  #pragma unroll
  for (int kt = 0; kt < NKT; ++kt) {
    bf16x8 bhf = *(const bf16x8*)&yh [16 * kt + l16][8 * g];
    bf16x8 blf = *(const bf16x8*)&ylo[16 * kt + l16][8 * g];
    f32x4 a = {0.f, 0.f, 0.f, 0.f};
    a = __builtin_amdgcn_mfma_f32_16x16x32_bf16(al, bhf, a, 0, 0, 0);
    a = __builtin_amdgcn_mfma_f32_16x16x32_bf16(ah, blf, a, 0, 0, 0);
    a = __builtin_amdgcn_mfma_f32_16x16x32_bf16(ah, bhf, a, 0, 0, 0);

    const int k = K0 + 16 * kt + l16;
    const bool kv = (k < K);
    const float y2  = y2l[16 * kt + l16];
    const float cy2 = c * y2;
    float ps = 0.f;
    #pragma unroll
    for (int reg = 0; reg < 4; ++reg) {
      const int t = 4 * g + reg;
      const bool tv = (t < T);
      const float dot = a[reg];
      const float A0 = fmaf(-tc, dot, 1.f);            // 1 + 2c*xy
      const float A  = A0 + cy2;                       // + c*y2
      const float dot2 = dot + dot;
      const float AB = A * Bcr[reg];
      float num2 = fmaf(A * A, x2r[reg],
                        fmaf(Bc2r[reg], y2, -AB * dot2));
      num2 = fmaxf(num2, 0.f);
      float den = fmaf(c2x2r[reg], y2, A0);
      den = fmaxf(den, MIN_NORM);
      float s_ = sc * __builtin_amdgcn_sqrtf(num2);
      s_ = fminf(s_, (1.f - EPSF) * den);              // z <= 1-eps
      float r   = (den + s_) * __builtin_amdgcn_rcpf(den - s_);
      float at2 = __builtin_amdgcn_logf(r);            // log2
      float d2  = KQ * at2 * at2;
      if (tv & kv)
        out1[(((size_t)(b * T + t)) * N + n) * K + k] = d2;
      ps += tv ? d2 : 0.f;
    }
    ps += __shfl_xor(ps, 16);
    ps += __shfl_xor(ps, 32);
    if (g == 0 && kv)
      out0[((size_t)b * N + n) * K + k] = ps * (1.f / (float)N);
  }
}

extern "C" void kernel_launch(void* const* d_in, const int* in_sizes, int n_in,
                              void* d_out, int out_size, void* d_ws, size_t ws_size,
                              hipStream_t stream) {
  // identify inputs by size (order-proof): node 998400, centroids 3200, c 1
  const void* xp = nullptr; const void* cwp = nullptr; const void* cp = nullptr;
  for (int i = 0; i < n_in; ++i) {
    if (in_sizes[i] == B * T * N * C)      xp  = d_in[i];
    else if (in_sizes[i] == K * C)         cwp = d_in[i];
    else if (in_sizes[i] == 1)             cp  = d_in[i];
  }
  if (!xp)  xp  = d_in[0];
  if (!cwp) cwp = d_in[1];
  if (!cp)  cp  = d_in[n_in - 1];

  float* out0 = (float*)d_out;                 // [B,N,K]
  float* out1 = out0 + (size_t)B * N * K;      // [B,T,N,K]

  // Two equal back-to-back dispatches (k 0..63 | k 64..99+pad).
  // Discriminator: per-dispatch floor => dur ~2x; real exec => dur ~unchanged.
  hipLaunchKernelGGL((hcd_half<0, 4>), dim3(B * NPAIRS), dim3(320), 0, stream,
                     (const float*)xp, (const float*)cwp, (const float*)cp,
                     out0, out1);
  hipLaunchKernelGGL((hcd_half<64, 3>), dim3(B * NPAIRS), dim3(320), 0, stream,
                     (const float*)xp, (const float*)cwp, (const float*)cp,
                     out0, out1);
}

// Round 13
// 16.554 us; speedup vs baseline: 1.2795x; 1.2795x over previous
//
#include <hip/hip_runtime.h>

namespace {
constexpr int B = 8, T = 12, N = 325, C = 32, K = 100;
constexpr int KPAD = 36;                      // 16B-aligned rows -> ds_read_b128
constexpr int NPB = 5;                        // nodes per block; 325 = 5*65
constexpr int NPAIRS = N / NPB;               // 65
constexpr float EPSF = 1e-5f;
constexpr float MIN_NORM = 1e-15f;
}

__global__ __launch_bounds__(512, 2) void hcd_kernel(
    const float* __restrict__ x_g,       // [B,T,N,C]
    const float* __restrict__ cw,        // [K,C]
    const float* __restrict__ cptr,      // [1]
    float* __restrict__ out0,            // [B,N,K]
    float* __restrict__ out1)            // [B,T,N,K]
{
  __shared__ float yl[K][KPAD];
  __shared__ float y2l[K];
  __shared__ float xl[NPB][T][KPAD];
  __shared__ float x2l[NPB][T];

  const int tid = threadIdx.x;
  const int b  = blockIdx.x / NPAIRS;
  const int np = blockIdx.x % NPAIRS;
  const int n0 = np * NPB;
  const float c  = cptr[0];
  const float sc = sqrtf(c);
  const float HLN2 = 0.34657359028f;            // ln2/2
  const float KQ = (4.f / c) * HLN2 * HLN2;     // (2/sc)^2*(ln2/2)^2
  const float TLOG2E = 2.88539008178f;          // 2*log2(e)

  // ---- stage x: 480 float4 loads (coalesced) ----
  for (int idx = tid; idx < NPB * T * (C / 4); idx += 512) {
    int nl = idx / (T * (C / 4));
    int r  = idx - nl * (T * (C / 4));
    int t  = r >> 3;
    int q  = r & 7;
    int n  = n0 + nl;
    float4 v = *(const float4*)(x_g + ((((size_t)(b * T + t)) * N + n) * C + 4 * q));
    *(float4*)&xl[nl][t][4 * q] = v;
  }

  // ---- expmap0(centroids), threads 0..99 ----
  if (tid < K) {
    float u[C];
    float u2 = 0.f;
    #pragma unroll
    for (int q = 0; q < C / 4; ++q) {
      float4 v = *(const float4*)(cw + tid * C + 4 * q);
      u[4*q+0] = v.x; u[4*q+1] = v.y; u[4*q+2] = v.z; u[4*q+3] = v.w;
    }
    #pragma unroll
    for (int i = 0; i < C; ++i) u2 = fmaf(u[i], u[i], u2);
    float z = sc * fmaxf(sqrtf(u2), MIN_NORM);
    float E  = exp2f(z * TLOG2E);                       // e^(2z)
    float th = (E - 1.f) * __builtin_amdgcn_rcpf(E + 1.f);
    float f  = th * __builtin_amdgcn_rcpf(z);
    #pragma unroll
    for (int q = 0; q < C / 4; ++q) {
      float4 v = make_float4(f*u[4*q+0], f*u[4*q+1], f*u[4*q+2], f*u[4*q+3]);
      *(float4*)&yl[tid][4 * q] = v;
    }
    y2l[tid] = f * f * u2;
  }
  __syncthreads();

  // ---- x squared norms (threads 0..59) ----
  if (tid < NPB * T) {
    int nl = tid / T, t = tid - nl * T;
    float s = 0.f;
    #pragma unroll
    for (int i = 0; i < C; ++i) s = fmaf(xl[nl][t][i], xl[nl][t][i], s);
    x2l[nl][t] = s;
  }
  __syncthreads();

  // ---- main: thread = (grp, k); 500/512 active ----
  const int grp = tid / K;        // 0..5
  const int k   = tid - grp * K;  // 0..99
  if (grp < NPB) {
    const int n = n0 + grp;

    float yk[C];
    #pragma unroll
    for (int q = 0; q < C / 4; ++q) {
      float4 v = *(const float4*)&yl[k][4 * q];
      yk[4*q+0] = v.x; yk[4*q+1] = v.y; yk[4*q+2] = v.z; yk[4*q+3] = v.w;
    }
    const float y2 = y2l[k];
    const float c2 = c * c;
    const float tc = 2.f * c;
    const float cy2 = c * y2;

    // 12 independent dot accumulators: q-outer, t-inner for ILP
    float d[T];
    #pragma unroll
    for (int t = 0; t < T; ++t) d[t] = 0.f;
    #pragma unroll
    for (int q = 0; q < C / 4; ++q) {
      #pragma unroll
      for (int t = 0; t < T; ++t) {
        float4 xv = *(const float4*)&xl[grp][t][4 * q];
        float acc = d[t];
        acc = fmaf(xv.x, yk[4*q+0], acc);
        acc = fmaf(xv.y, yk[4*q+1], acc);
        acc = fmaf(xv.z, yk[4*q+2], acc);
        acc = fmaf(xv.w, yk[4*q+3], acc);
        d[t] = acc;
      }
    }

    // 12 independent epilogues; non-temporal streaming stores
    float ssum = 0.f;
    #pragma unroll
    for (int t = 0; t < T; ++t) {
      const float x2 = x2l[grp][t];
      const float dot = d[t];
      const float A0 = fmaf(-tc, dot, 1.f);               // 1 + 2c*xy
      const float A  = A0 + cy2;                          // + c*y2
      const float Bc = fmaf(-c, x2, 1.f);                 // 1 - c*x2
      const float AB = A * Bc;
      float num2 = fmaf(A * A, x2, fmaf(Bc * Bc, y2, -AB * (dot + dot)));
      num2 = fmaxf(num2, 0.f);
      float den = fmaf(c2 * x2, y2, A0);
      den = fmaxf(den, MIN_NORM);
      float s_ = sc * __builtin_amdgcn_sqrtf(num2);
      s_ = fminf(s_, (1.f - EPSF) * den);                 // z <= 1-eps
      float r   = (den + s_) * __builtin_amdgcn_rcpf(den - s_);
      float at2 = __builtin_amdgcn_logf(r);               // log2 ratio
      float d2  = KQ * at2 * at2;
      ssum += d2;
      __builtin_nontemporal_store(
          d2, &out1[(((size_t)(b * T + t)) * N + n) * K + k]);
    }
    __builtin_nontemporal_store(
        ssum * (1.f / (float)N), &out0[((size_t)b * N + n) * K + k]);
  }
}

extern "C" void kernel_launch(void* const* d_in, const int* in_sizes, int n_in,
                              void* d_out, int out_size, void* d_ws, size_t ws_size,
                              hipStream_t stream) {
  // identify inputs by size (order-proof): node 998400, centroids 3200, c 1
  const void* xp = nullptr; const void* cwp = nullptr; const void* cp = nullptr;
  for (int i = 0; i < n_in; ++i) {
    if (in_sizes[i] == B * T * N * C)      xp  = d_in[i];
    else if (in_sizes[i] == K * C)         cwp = d_in[i];
    else if (in_sizes[i] == 1)             cp  = d_in[i];
  }
  if (!xp)  xp  = d_in[0];
  if (!cwp) cwp = d_in[1];
  if (!cp)  cp  = d_in[n_in - 1];

  float* out0 = (float*)d_out;                 // [B,N,K]
  float* out1 = out0 + (size_t)B * N * K;      // [B,T,N,K]

  hipLaunchKernelGGL(hcd_kernel, dim3(B * NPAIRS), dim3(512), 0, stream,
                     (const float*)xp, (const float*)cwp, (const float*)cp,
                     out0, out1);
}

// Round 14
// 16.446 us; speedup vs baseline: 1.2879x; 1.0066x over previous
//
#include <hip/hip_runtime.h>

namespace {
constexpr int B = 8, T = 12, N = 325, C = 32, K = 100;
constexpr int KPAD = 36;                      // 16B-aligned rows -> ds_read_b128
constexpr int NPB = 5;                        // nodes per block; 325 = 5*65
constexpr int NPAIRS = N / NPB;               // 65
constexpr float EPSF = 1e-5f;
constexpr float MIN_NORM = 1e-15f;
}

__global__ __launch_bounds__(512, 4) void hcd_kernel(   // 2 blocks/CU, 4 waves/SIMD
    const float* __restrict__ x_g,       // [B,T,N,C]
    const float* __restrict__ cw,        // [K,C]
    const float* __restrict__ cptr,      // [1]
    float* __restrict__ out0,            // [B,N,K]
    float* __restrict__ out1)            // [B,T,N,K]
{
  __shared__ float yl[K][KPAD];
  __shared__ float y2l[K];
  __shared__ float xl[NPB][T][KPAD];
  __shared__ float x2l[NPB][T];

  const int tid = threadIdx.x;
  const int b  = blockIdx.x / NPAIRS;
  const int np = blockIdx.x % NPAIRS;
  const int n0 = np * NPB;
  const float c  = cptr[0];
  const float sc = sqrtf(c);
  const float HLN2 = 0.34657359028f;            // ln2/2
  const float KQ = (4.f / c) * HLN2 * HLN2;     // (2/sc)^2*(ln2/2)^2
  const float TLOG2E = 2.88539008178f;          // 2*log2(e)

  // ---- stage x (480 float4 loads) + in-wave x2 reduction ----
  // idx = nl*96 + t*8 + q ; the 8 q-lanes of one (nl,t) row are consecutive
  // lanes within one wave (96 = 12*8, rows 8-aligned, never split at 64).
  if (tid < NPB * T * (C / 4)) {
    int nl = tid / (T * (C / 4));
    int r  = tid - nl * (T * (C / 4));
    int t  = r >> 3;
    int q  = r & 7;
    int n  = n0 + nl;
    float4 v = *(const float4*)(x_g + ((((size_t)(b * T + t)) * N + n) * C + 4 * q));
    *(float4*)&xl[nl][t][4 * q] = v;
    float pp = fmaf(v.x, v.x, fmaf(v.y, v.y, fmaf(v.z, v.z, v.w * v.w)));
    pp += __shfl_xor(pp, 1);
    pp += __shfl_xor(pp, 2);
    pp += __shfl_xor(pp, 4);
    if (q == 0) x2l[nl][t] = pp;
  }

  // ---- expmap0(centroids), threads 0..99 (concurrent with staging) ----
  if (tid < K) {
    float u[C];
    float u2 = 0.f;
    #pragma unroll
    for (int q = 0; q < C / 4; ++q) {
      float4 v = *(const float4*)(cw + tid * C + 4 * q);
      u[4*q+0] = v.x; u[4*q+1] = v.y; u[4*q+2] = v.z; u[4*q+3] = v.w;
    }
    #pragma unroll
    for (int i = 0; i < C; ++i) u2 = fmaf(u[i], u[i], u2);
    float z = sc * fmaxf(sqrtf(u2), MIN_NORM);
    float E  = exp2f(z * TLOG2E);                       // e^(2z)
    float th = (E - 1.f) * __builtin_amdgcn_rcpf(E + 1.f);
    float f  = th * __builtin_amdgcn_rcpf(z);
    #pragma unroll
    for (int q = 0; q < C / 4; ++q) {
      float4 v = make_float4(f*u[4*q+0], f*u[4*q+1], f*u[4*q+2], f*u[4*q+3]);
      *(float4*)&yl[tid][4 * q] = v;
    }
    y2l[tid] = f * f * u2;
  }
  __syncthreads();

  // ---- main: thread = (grp, k); 500/512 active ----
  const int grp = tid / K;        // 0..5
  const int k   = tid - grp * K;  // 0..99
  if (grp < NPB) {
    const int n = n0 + grp;

    float yk[C];
    #pragma unroll
    for (int q = 0; q < C / 4; ++q) {
      float4 v = *(const float4*)&yl[k][4 * q];
      yk[4*q+0] = v.x; yk[4*q+1] = v.y; yk[4*q+2] = v.z; yk[4*q+3] = v.w;
    }
    const float y2 = y2l[k];
    const float c2 = c * c;
    const float tc = 2.f * c;
    const float cy2 = c * y2;

    // 12 independent dot accumulators: q-outer, t-inner for ILP
    float d[T];
    #pragma unroll
    for (int t = 0; t < T; ++t) d[t] = 0.f;
    #pragma unroll
    for (int q = 0; q < C / 4; ++q) {
      #pragma unroll
      for (int t = 0; t < T; ++t) {
        float4 xv = *(const float4*)&xl[grp][t][4 * q];
        float acc = d[t];
        acc = fmaf(xv.x, yk[4*q+0], acc);
        acc = fmaf(xv.y, yk[4*q+1], acc);
        acc = fmaf(xv.z, yk[4*q+2], acc);
        acc = fmaf(xv.w, yk[4*q+3], acc);
        d[t] = acc;
      }
    }

    // 12 independent epilogues; non-temporal streaming stores
    float ssum = 0.f;
    #pragma unroll
    for (int t = 0; t < T; ++t) {
      const float x2 = x2l[grp][t];
      const float dot = d[t];
      const float A0 = fmaf(-tc, dot, 1.f);               // 1 + 2c*xy
      const float A  = A0 + cy2;                          // + c*y2
      const float Bc = fmaf(-c, x2, 1.f);                 // 1 - c*x2
      const float AB = A * Bc;
      float num2 = fmaf(A * A, x2, fmaf(Bc * Bc, y2, -AB * (dot + dot)));
      num2 = fmaxf(num2, 0.f);
      float den = fmaf(c2 * x2, y2, A0);
      den = fmaxf(den, MIN_NORM);
      float s_ = sc * __builtin_amdgcn_sqrtf(num2);
      s_ = fminf(s_, (1.f - EPSF) * den);                 // z <= 1-eps
      float r   = (den + s_) * __builtin_amdgcn_rcpf(den - s_);
      float at2 = __builtin_amdgcn_logf(r);               // log2 ratio
      float d2  = KQ * at2 * at2;
      ssum += d2;
      __builtin_nontemporal_store(
          d2, &out1[(((size_t)(b * T + t)) * N + n) * K + k]);
    }
    __builtin_nontemporal_store(
        ssum * (1.f / (float)N), &out0[((size_t)b * N + n) * K + k]);
  }
}

extern "C" void kernel_launch(void* const* d_in, const int* in_sizes, int n_in,
                              void* d_out, int out_size, void* d_ws, size_t ws_size,
                              hipStream_t stream) {
  // identify inputs by size (order-proof): node 998400, centroids 3200, c 1
  const void* xp = nullptr; const void* cwp = nullptr; const void* cp = nullptr;
  for (int i = 0; i < n_in; ++i) {
    if (in_sizes[i] == B * T * N * C)      xp  = d_in[i];
    else if (in_sizes[i] == K * C)         cwp = d_in[i];
    else if (in_sizes[i] == 1)             cp  = d_in[i];
  }
  if (!xp)  xp  = d_in[0];
  if (!cwp) cwp = d_in[1];
  if (!cp)  cp  = d_in[n_in - 1];

  float* out0 = (float*)d_out;                 // [B,N,K]
  float* out1 = out0 + (size_t)B * N * K;      // [B,T,N,K]

  hipLaunchKernelGGL(hcd_kernel, dim3(B * NPAIRS), dim3(512), 0, stream,
                     (const float*)xp, (const float*)cwp, (const float*)cp,
                     out0, out1);
}